// Round 2
// baseline (1251.376 us; speedup 1.0000x reference)
//
#include <hip/hip_runtime.h>
#include <math.h>

#define BB 2
#define NQ 4096
#define NC 8192
#define HC 64
#define KNN 32
#define CAP 1024
#define LDA 132
#define BN_EPS 1e-5f

// ---------------- Kernel 1: radius-filtered top-32 (float64 exact ordering) ----------------
__global__ __launch_bounds__(256) void knn_kernel(
    const float* __restrict__ pq, const float* __restrict__ pc,
    int* __restrict__ idx_out, float* __restrict__ cw_out)
{
    const int q = blockIdx.x, b = blockIdx.y, tid = threadIdx.x;
    const int gq = b * NQ + q;
    __shared__ unsigned long long kd[CAP];
    __shared__ int pid[CAP];
    __shared__ int cnt;
    if (tid == 0) cnt = 0;
    __syncthreads();

    const double qx = (double)pq[gq*3+0];
    const double qy = (double)pq[gq*3+1];
    const double qz = (double)pq[gq*3+2];
    const double sq = qx*qx + qy*qy + qz*qz;
    const double R2d = 0.2 * 0.2;   // matches python RADIUS**2 in double
    const float* pcb = pc + (size_t)b * NC * 3;

    for (int n = tid; n < NC; n += 256) {
        double cx = (double)pcb[n*3+0];
        double cy = (double)pcb[n*3+1];
        double cz = (double)pcb[n*3+2];
        double dot = qx*cx + qy*cy + qz*cz;
        double sc  = cx*cx + cy*cy + cz*cz;
        double d   = (sq - 2.0*dot) + sc;
        if (d <= R2d) {
            int p = atomicAdd(&cnt, 1);
            if (p < CAP) {
                double dc = d < 0.0 ? 0.0 : d;   // non-positive -> weight 0 either way
                kd[p]  = (unsigned long long)__double_as_longlong(dc); // monotone for >=0
                pid[p] = n;
            }
        }
    }
    __syncthreads();
    int M = cnt < CAP ? cnt : CAP;
    int P = 32; while (P < M) P <<= 1;
    for (int i = M + tid; i < P; i += 256) { kd[i] = ~0ULL; pid[i] = 0x7fffffff; }
    __syncthreads();

    // bitonic sort ascending by (d, idx) — matches top_k stable lower-index-first
    for (int kk = 2; kk <= P; kk <<= 1) {
        for (int j = kk >> 1; j > 0; j >>= 1) {
            for (int t = tid; t < P; t += 256) {
                int ixj = t ^ j;
                if (ixj > t) {
                    unsigned long long a = kd[t], c = kd[ixj];
                    int pa = pid[t], pb_ = pid[ixj];
                    bool up  = ((t & kk) == 0);
                    bool agt = (a > c) || (a == c && pa > pb_);
                    bool alt = (a < c) || (a == c && pa < pb_);
                    if (up ? agt : alt) {
                        kd[t] = c; kd[ixj] = a;
                        pid[t] = pb_; pid[ixj] = pa;
                    }
                }
            }
            __syncthreads();
        }
    }

    if (tid < KNN) {
        unsigned long long key = kd[tid];
        int id = 0; float c = 0.0f;
        if (key != ~0ULL) {
            id = pid[tid];
            double d = __longlong_as_double((long long)key);
            if (d > 0.0 && d <= 0.2) {
                double cw = 0.5 * (cos(d * 15.707963267948966) + 1.0);
                c = (float)cw;
            }
        }
        idx_out[gq*KNN + tid] = id;
        cw_out[gq*KNN + tid]  = c;
    }
}

// ---------------- Kernel 2: fused MLP ----------------
__device__ inline void stage_wt(float* Wt, const float* __restrict__ Wsrc, int tid)
{
    // Wsrc: [128 out][128 in] row-major -> Wt[k*LDA + j]
    for (int p = tid; p < 128*128; p += 256) {
        int j = p >> 7, k = p & 127;
        Wt[k*LDA + j] = Wsrc[p];
    }
}

__device__ inline void layer128(const float* __restrict__ Asrc, const float* __restrict__ Wt,
                                float* __restrict__ Dst,
                                const float* __restrict__ bias, const float* __restrict__ g,
                                const float* __restrict__ be, const float* __restrict__ m,
                                const float* __restrict__ v, int joff, bool relu, int tid)
{
    const int rg = tid >> 5, cg = tid & 31;
    float acc[4][4] = {};
    for (int k = 0; k < 128; k += 4) {
        float a[4][4], w[4][4];
#pragma unroll
        for (int r = 0; r < 4; ++r)
            *(float4*)&a[r][0] = *(const float4*)&Asrc[(rg*4+r)*LDA + k];
#pragma unroll
        for (int t = 0; t < 4; ++t)
            *(float4*)&w[t][0] = *(const float4*)&Wt[(k+t)*LDA + cg*4];
#pragma unroll
        for (int r = 0; r < 4; ++r)
#pragma unroll
            for (int t = 0; t < 4; ++t)
#pragma unroll
                for (int c = 0; c < 4; ++c)
                    acc[r][c] += a[r][t] * w[t][c];
    }
#pragma unroll
    for (int c = 0; c < 4; ++c) {
        int j = cg*4 + c, jg = joff + j;
        float rs = rsqrtf(v[jg] + BN_EPS);
        float gg = g[jg], mm = m[jg], bb = be[jg], bi = bias[jg];
#pragma unroll
        for (int r = 0; r < 4; ++r) {
            float x = acc[r][c] + bi;
            float o = gg * ((x - mm) * rs) + bb;
            if (relu) o = fmaxf(o, 0.0f);
            Dst[(rg*4+r)*LDA + j] = o;
        }
    }
}

__global__ __launch_bounds__(256) void mlp_kernel(
    const float* __restrict__ pq, const float* __restrict__ pc, const float* __restrict__ hc,
    const float* __restrict__ w_xyz, const float* __restrict__ b_xyz,
    const float* __restrict__ w1, const float* __restrict__ b1,
    const float* __restrict__ g1, const float* __restrict__ be1,
    const float* __restrict__ m1, const float* __restrict__ v1,
    const float* __restrict__ w2, const float* __restrict__ b2,
    const float* __restrict__ g2, const float* __restrict__ be2,
    const float* __restrict__ m2, const float* __restrict__ v2,
    const float* __restrict__ w3, const float* __restrict__ b3,
    const float* __restrict__ g3, const float* __restrict__ be3,
    const float* __restrict__ m3, const float* __restrict__ v3,
    const float* __restrict__ gw1, const float* __restrict__ gb1,
    const float* __restrict__ gg1, const float* __restrict__ gbe1,
    const float* __restrict__ gm1, const float* __restrict__ gv1,
    const float* __restrict__ gw2, const float* __restrict__ gb2,
    const float* __restrict__ gg2, const float* __restrict__ gbe2,
    const float* __restrict__ gm2, const float* __restrict__ gv2,
    const float* __restrict__ gw3, const float* __restrict__ gb3,
    const int* __restrict__ idx_in, const float* __restrict__ cw_in,
    float* __restrict__ out)
{
    const int q = blockIdx.x, b = blockIdx.y, tid = threadIdx.x;
    const int gq = b * NQ + q;

    __shared__ float A[KNN*LDA];
    __shared__ float Bf[KNN*LDA];
    __shared__ float Wt[128*LDA];
    __shared__ float Prel[KNN*4];
    __shared__ float Cw[KNN];
    __shared__ int   Sidx[KNN];
    __shared__ float Y0[256], Y1[128], Y2[64];

    const float qx = pq[gq*3+0], qy = pq[gq*3+1], qz = pq[gq*3+2];
    const float* pcb = pc + (size_t)b * NC * 3;
    const float* hcb = hc + (size_t)b * NC * HC;

    // S0: load idx / c / p_rel
    if (tid < KNN) {
        int id = idx_in[gq*KNN + tid];
        Sidx[tid] = id;
        Cw[tid]   = cw_in[gq*KNN + tid];
        Prel[tid*4+0] = pcb[id*3+0] - qx;
        Prel[tid*4+1] = pcb[id*3+1] - qy;
        Prel[tid*4+2] = pcb[id*3+2] - qz;
    }
    __syncthreads();

    // S1: build h = [h_rel | h_group] into A; stage W1
    for (int p = tid; p < KNN*HC; p += 256) {
        int i = p >> 6, c = p & 63;
        A[i*LDA + 64 + c] = hcb[(size_t)Sidx[i]*HC + c];
    }
    for (int p = tid; p < KNN*64; p += 256) {
        int i = p >> 6, c = p & 63;
        float hr = (Prel[i*4+0]*w_xyz[c*3+0] + Prel[i*4+1]*w_xyz[c*3+1])
                 + Prel[i*4+2]*w_xyz[c*3+2] + b_xyz[c];
        A[i*LDA + c] = hr;
    }
    stage_wt(Wt, w1, tid);
    __syncthreads();

    // L1: A -> Bf
    layer128(A, Wt, Bf, b1, g1, be1, m1, v1, 0, true, tid);
    __syncthreads();
    stage_wt(Wt, w2, tid);
    __syncthreads();
    // L2: Bf -> A
    layer128(Bf, Wt, A, b2, g2, be2, m2, v2, 0, true, tid);
    __syncthreads();
    stage_wt(Wt, w3, tid);   // first 128 output cols of w3
    __syncthreads();
    // L3 half 0: A -> Bf
    layer128(A, Wt, Bf, b3, g3, be3, m3, v3, 0, false, tid);
    __syncthreads();
    // reduce half 0; stage w3 half 1 concurrently
    if (tid < 128) {
        float s = 0.0f;
#pragma unroll
        for (int i = 0; i < KNN; ++i) s += Bf[i*LDA + tid] * Cw[i];
        Y0[tid] = s;
    }
    stage_wt(Wt, w3 + 128*128, tid);
    __syncthreads();
    // L3 half 1: A -> Bf
    layer128(A, Wt, Bf, b3, g3, be3, m3, v3, 128, false, tid);
    __syncthreads();
    if (tid < 128) {
        float s = 0.0f;
#pragma unroll
        for (int i = 0; i < KNN; ++i) s += Bf[i*LDA + tid] * Cw[i];
        Y0[128 + tid] = s;
    }
    __syncthreads();

    // ---- g-MLP ----
    float gacc = 0.0f;
    for (int kc = 0; kc < 2; ++kc) {
        for (int p = tid; p < 128*128; p += 256) {
            int j = p >> 7, k = p & 127;
            Wt[k*LDA + j] = gw1[j*256 + kc*128 + k];
        }
        __syncthreads();
        if (tid < 128) {
            float s = 0.0f;
            for (int k = 0; k < 128; ++k) s += Y0[kc*128 + k] * Wt[k*LDA + tid];
            gacc += s;
        }
        __syncthreads();
    }
    if (tid < 128) {
        float x = gacc + gb1[tid];
        float rs = rsqrtf(gv1[tid] + BN_EPS);
        float o = gg1[tid] * ((x - gm1[tid]) * rs) + gbe1[tid];
        Y1[tid] = fmaxf(o, 0.0f);
    }
    __syncthreads();
    for (int p = tid; p < 64*128; p += 256) {
        int j = p >> 7, k = p & 127;
        Wt[k*LDA + j] = gw2[p];
    }
    __syncthreads();
    if (tid < 64) {
        float s = 0.0f;
        for (int k = 0; k < 128; ++k) s += Y1[k] * Wt[k*LDA + tid];
        float x = s + gb2[tid];
        float rs = rsqrtf(gv2[tid] + BN_EPS);
        float o = gg2[tid] * ((x - gm2[tid]) * rs) + gbe2[tid];
        Y2[tid] = fmaxf(o, 0.0f);
    }
    __syncthreads();
    if (tid < 3) {
        float s = 0.0f;
        for (int k = 0; k < 64; ++k) s += Y2[k] * gw3[tid*64 + k];
        out[gq*3 + tid] = s + gb3[tid];
    }
}

extern "C" void kernel_launch(void* const* d_in, const int* in_sizes, int n_in,
                              void* d_out, int out_size, void* d_ws, size_t ws_size,
                              hipStream_t stream)
{
    const float* pq    = (const float*)d_in[0];
    const float* pc    = (const float*)d_in[1];
    const float* hc    = (const float*)d_in[2];
    const float* w_xyz = (const float*)d_in[3];
    const float* b_xyz = (const float*)d_in[4];
    const float* w1    = (const float*)d_in[5];
    const float* b1    = (const float*)d_in[6];
    const float* g1    = (const float*)d_in[7];
    const float* be1   = (const float*)d_in[8];
    const float* m1    = (const float*)d_in[9];
    const float* v1    = (const float*)d_in[10];
    const float* w2    = (const float*)d_in[11];
    const float* b2    = (const float*)d_in[12];
    const float* g2    = (const float*)d_in[13];
    const float* be2   = (const float*)d_in[14];
    const float* m2    = (const float*)d_in[15];
    const float* v2    = (const float*)d_in[16];
    const float* w3    = (const float*)d_in[17];
    const float* b3    = (const float*)d_in[18];
    const float* g3    = (const float*)d_in[19];
    const float* be3   = (const float*)d_in[20];
    const float* m3    = (const float*)d_in[21];
    const float* v3    = (const float*)d_in[22];
    const float* gw1   = (const float*)d_in[23];
    const float* gb1   = (const float*)d_in[24];
    const float* gg1   = (const float*)d_in[25];
    const float* gbe1  = (const float*)d_in[26];
    const float* gm1   = (const float*)d_in[27];
    const float* gv1   = (const float*)d_in[28];
    const float* gw2   = (const float*)d_in[29];
    const float* gb2   = (const float*)d_in[30];
    const float* gg2   = (const float*)d_in[31];
    const float* gbe2  = (const float*)d_in[32];
    const float* gm2   = (const float*)d_in[33];
    const float* gv2   = (const float*)d_in[34];
    const float* gw3   = (const float*)d_in[35];
    const float* gb3   = (const float*)d_in[36];

    int*   idx_buf = (int*)d_ws;
    float* cw_buf  = (float*)((char*)d_ws + (size_t)BB*NQ*KNN*sizeof(int));

    dim3 grid(NQ, BB);
    knn_kernel<<<grid, 256, 0, stream>>>(pq, pc, idx_buf, cw_buf);
    mlp_kernel<<<grid, 256, 0, stream>>>(pq, pc, hc, w_xyz, b_xyz,
        w1, b1, g1, be1, m1, v1,
        w2, b2, g2, be2, m2, v2,
        w3, b3, g3, be3, m3, v3,
        gw1, gb1, gg1, gbe1, gm1, gv1,
        gw2, gb2, gg2, gbe2, gm2, gv2,
        gw3, gb3,
        idx_buf, cw_buf, (float*)d_out);
}

// Round 3
// 858.926 us; speedup vs baseline: 1.4569x; 1.4569x over previous
//
#include <hip/hip_runtime.h>
#include <hip/hip_bf16.h>
#include <math.h>

#define BB 2
#define NQ 4096
#define NC 8192
#define KNN 32
#define CAP 1024
#define QB 8
#define MROWS 256   // QB*KNN
#define BN_EPS 1e-5f

typedef __attribute__((ext_vector_type(8))) short s16x8;
typedef __attribute__((ext_vector_type(4))) float f32x4;

__device__ inline int swzb(int row, int kbyte) {
    return (row * 256 + kbyte) ^ ((row & 7) << 4);
}
__device__ inline unsigned short f2bf(float x) {
    __hip_bfloat16 h = __float2bfloat16(x);
    return *reinterpret_cast<unsigned short*>(&h);
}
__device__ inline float bf2f(unsigned short u) {
    return __uint_as_float(((unsigned)u) << 16);
}

// ---------------- Kernel 1: radius-filtered top-32 (float64 exact ordering) ----------------
__global__ __launch_bounds__(256) void knn_kernel(
    const float* __restrict__ pq, const float* __restrict__ pc,
    int* __restrict__ idx_out, float* __restrict__ cw_out)
{
    const int q = blockIdx.x, b = blockIdx.y, tid = threadIdx.x;
    const int gq = b * NQ + q;
    __shared__ unsigned long long kd[CAP];
    __shared__ int pid[CAP];
    __shared__ int cnt;
    if (tid == 0) cnt = 0;
    __syncthreads();

    const double qx = (double)pq[gq*3+0];
    const double qy = (double)pq[gq*3+1];
    const double qz = (double)pq[gq*3+2];
    const double sq = qx*qx + qy*qy + qz*qz;
    const double R2d = 0.2 * 0.2;
    const float* pcb = pc + (size_t)b * NC * 3;

    for (int n = tid; n < NC; n += 256) {
        double cx = (double)pcb[n*3+0];
        double cy = (double)pcb[n*3+1];
        double cz = (double)pcb[n*3+2];
        double dot = qx*cx + qy*cy + qz*cz;
        double sc  = cx*cx + cy*cy + cz*cz;
        double d   = (sq - 2.0*dot) + sc;
        if (d <= R2d) {
            int p = atomicAdd(&cnt, 1);
            if (p < CAP) {
                double dc = d < 0.0 ? 0.0 : d;
                kd[p]  = (unsigned long long)__double_as_longlong(dc);
                pid[p] = n;
            }
        }
    }
    __syncthreads();
    int M = cnt < CAP ? cnt : CAP;
    int P = 32; while (P < M) P <<= 1;
    for (int i = M + tid; i < P; i += 256) { kd[i] = ~0ULL; pid[i] = 0x7fffffff; }
    __syncthreads();

    for (int kk = 2; kk <= P; kk <<= 1) {
        for (int j = kk >> 1; j > 0; j >>= 1) {
            for (int t = tid; t < P; t += 256) {
                int ixj = t ^ j;
                if (ixj > t) {
                    unsigned long long a = kd[t], c = kd[ixj];
                    int pa = pid[t], pb_ = pid[ixj];
                    bool up  = ((t & kk) == 0);
                    bool agt = (a > c) || (a == c && pa > pb_);
                    bool alt = (a < c) || (a == c && pa < pb_);
                    if (up ? agt : alt) {
                        kd[t] = c; kd[ixj] = a;
                        pid[t] = pb_; pid[ixj] = pa;
                    }
                }
            }
            __syncthreads();
        }
    }

    if (tid < KNN) {
        unsigned long long key = kd[tid];
        int id = 0; float c = 0.0f;
        if (key != ~0ULL) {
            id = pid[tid];
            double d = __longlong_as_double((long long)key);
            if (d > 0.0 && d <= 0.2) {
                double cw = 0.5 * (cos(d * 15.707963267948966) + 1.0);
                c = (float)cw;
            }
        }
        idx_out[gq*KNN + tid] = id;
        cw_out[gq*KNN + tid]  = c;
    }
}

// ---------------- Kernel 2: fused MFMA MLP, 8 queries/block ----------------
__global__ __launch_bounds__(512) void mlp_kernel(
    const float* __restrict__ pq, const float* __restrict__ pc, const float* __restrict__ hc,
    const float* __restrict__ w_xyz, const float* __restrict__ b_xyz,
    const float* __restrict__ w1, const float* __restrict__ b1,
    const float* __restrict__ g1, const float* __restrict__ be1,
    const float* __restrict__ m1, const float* __restrict__ v1,
    const float* __restrict__ w2, const float* __restrict__ b2,
    const float* __restrict__ g2, const float* __restrict__ be2,
    const float* __restrict__ m2, const float* __restrict__ v2,
    const float* __restrict__ w3, const float* __restrict__ b3,
    const float* __restrict__ g3, const float* __restrict__ be3,
    const float* __restrict__ m3, const float* __restrict__ v3,
    const float* __restrict__ gw1, const float* __restrict__ gb1,
    const float* __restrict__ gg1, const float* __restrict__ gbe1,
    const float* __restrict__ gm1, const float* __restrict__ gv1,
    const float* __restrict__ gw2, const float* __restrict__ gb2,
    const float* __restrict__ gg2, const float* __restrict__ gbe2,
    const float* __restrict__ gm2, const float* __restrict__ gv2,
    const float* __restrict__ gw3, const float* __restrict__ gb3,
    const int* __restrict__ idx_in, const float* __restrict__ cw_in,
    float* __restrict__ out)
{
    __shared__ __align__(16) unsigned short Asm[MROWS*128];     // 64 KB activations (bf16)
    __shared__ __align__(16) unsigned short Wsm[2][128*128];    // 2x32 KB weights (bf16)
    __shared__ float Prel[MROWS*3];
    __shared__ float Cw[MROWS];
    __shared__ int   Sidx[MROWS];
    __shared__ float Sfd[2][2][128];
    __shared__ float Sq[QB];
    __shared__ float Zs[QB*128];
    __shared__ float Y0s[QB*256];
    __shared__ float Y1s[QB*128];
    __shared__ float Y2s[QB*64];

    const int tid = threadIdx.x;
    const int qbase = blockIdx.x * QB;        // flattened query index (0..8191)
    const int b = qbase >> 12;                // batch
    const float* pcb = pc + (size_t)b * NC * 3;
    const float* hcb = hc + (size_t)b * NC * 64;

    // ---- phase 0: idx / cw / p_rel ----
    if (tid < MROWS) {
        int id = idx_in[qbase*KNN + tid];
        Sidx[tid] = id;
        Cw[tid]   = cw_in[qbase*KNN + tid];
        int gq = qbase + (tid >> 5);
        Prel[tid*3+0] = pcb[id*3+0] - pq[gq*3+0];
        Prel[tid*3+1] = pcb[id*3+1] - pq[gq*3+1];
        Prel[tid*3+2] = pcb[id*3+2] - pq[gq*3+2];
    }
    __syncthreads();

    // ---- phase 1: build A (bf16, swizzled), stage W1/W2, fold BN params ----
    char* Ab = (char*)Asm;
    for (int p = tid; p < MROWS*16; p += 512) {
        int row = p >> 4, seg = p & 15;
        float vals[8];
        if (seg >= 8) {
            const float* src = hcb + (size_t)Sidx[row]*64 + (seg-8)*8;
            float4 u0 = *(const float4*)src;
            float4 u1 = *(const float4*)(src+4);
            vals[0]=u0.x; vals[1]=u0.y; vals[2]=u0.z; vals[3]=u0.w;
            vals[4]=u1.x; vals[5]=u1.y; vals[6]=u1.z; vals[7]=u1.w;
        } else {
            float px = Prel[row*3+0], py = Prel[row*3+1], pz = Prel[row*3+2];
            int c0 = seg*8;
#pragma unroll
            for (int j = 0; j < 8; ++j) {
                int c = c0 + j;
                vals[j] = px*w_xyz[c*3+0] + py*w_xyz[c*3+1] + pz*w_xyz[c*3+2] + b_xyz[c];
            }
        }
        union { s16x8 v; unsigned short u[8]; } pk;
#pragma unroll
        for (int j = 0; j < 8; ++j) pk.u[j] = f2bf(vals[j]);
        *(s16x8*)(Ab + swzb(row, seg*16)) = pk.v;
    }
    for (int L = 0; L < 2; ++L) {
        const float* wsrc = L ? w2 : w1;
        char* Wb = (char*)Wsm[L];
        for (int p = tid; p < 128*16; p += 512) {
            int row = p >> 4, seg = p & 15;
            const float* src = wsrc + row*128 + seg*8;
            float4 u0 = *(const float4*)src;
            float4 u1 = *(const float4*)(src+4);
            union { s16x8 v; unsigned short u[8]; } pk;
            pk.u[0]=f2bf(u0.x); pk.u[1]=f2bf(u0.y); pk.u[2]=f2bf(u0.z); pk.u[3]=f2bf(u0.w);
            pk.u[4]=f2bf(u1.x); pk.u[5]=f2bf(u1.y); pk.u[6]=f2bf(u1.z); pk.u[7]=f2bf(u1.w);
            *(s16x8*)(Wb + swzb(row, seg*16)) = pk.v;
        }
    }
    if (tid < 128) {
        int j = tid;
        float s0 = g1[j] * rsqrtf(v1[j] + BN_EPS);
        Sfd[0][0][j] = s0; Sfd[0][1][j] = s0*(b1[j]-m1[j]) + be1[j];
        float s1 = g2[j] * rsqrtf(v2[j] + BN_EPS);
        Sfd[1][0][j] = s1; Sfd[1][1][j] = s1*(b2[j]-m2[j]) + be2[j];
    }
    if (tid < QB) {
        float s = 0.0f;
        for (int i = 0; i < KNN; ++i) s += Cw[tid*KNN + i];
        Sq[tid] = s;
    }
    __syncthreads();

    // ---- phase 2: L1 and L2 via MFMA (each wave owns 32 rows = 1 query) ----
    const int l = tid & 63, w = tid >> 6;
    const int r0 = w * 32, cl = l & 15, q4 = l >> 4;

#pragma unroll
    for (int L = 0; L < 2; ++L) {
        const char* Wb = (const char*)Wsm[L];
        f32x4 acc[2][8];
#pragma unroll
        for (int mt = 0; mt < 2; ++mt)
#pragma unroll
            for (int nt = 0; nt < 8; ++nt)
                acc[mt][nt] = (f32x4){0.f,0.f,0.f,0.f};
#pragma unroll
        for (int kk = 0; kk < 4; ++kk) {
            int kbyte = kk*64 + q4*16;
            s16x8 a0 = *(const s16x8*)(Ab + swzb(r0 + cl,      kbyte));
            s16x8 a1 = *(const s16x8*)(Ab + swzb(r0 + 16 + cl, kbyte));
            s16x8 bw[8];
#pragma unroll
            for (int nt = 0; nt < 8; ++nt)
                bw[nt] = *(const s16x8*)(Wb + swzb(nt*16 + cl, kbyte));
#pragma unroll
            for (int nt = 0; nt < 8; ++nt) {
                acc[0][nt] = __builtin_amdgcn_mfma_f32_16x16x32_bf16(a0, bw[nt], acc[0][nt], 0, 0, 0);
                acc[1][nt] = __builtin_amdgcn_mfma_f32_16x16x32_bf16(a1, bw[nt], acc[1][nt], 0, 0, 0);
            }
        }
        // epilogue: folded BN + ReLU, write back bf16 in place (wave-private rows)
#pragma unroll
        for (int nt = 0; nt < 8; ++nt) {
            int j = nt*16 + cl;
            float s = Sfd[L][0][j], t = Sfd[L][1][j];
#pragma unroll
            for (int mt = 0; mt < 2; ++mt)
#pragma unroll
                for (int r = 0; r < 4; ++r) {
                    int row = r0 + mt*16 + q4*4 + r;
                    float x = fmaxf(acc[mt][nt][r]*s + t, 0.0f);
                    *(unsigned short*)(Ab + swzb(row, j*2)) = f2bf(x);
                }
        }
        // no barrier needed: each wave reads/writes only its own 32 rows
    }
    __syncthreads();

    // ---- phase 3: z[q] = sum_i c_i * A2[q,i,:]  (layer-3 commuted) ----
    for (int p = tid; p < QB*128; p += 512) {
        int q = p >> 7, col = p & 127;
        float s = 0.0f;
#pragma unroll
        for (int i = 0; i < KNN; ++i) {
            unsigned short u = *(const unsigned short*)(Ab + swzb(q*KNN + i, col*2));
            s += Cw[q*KNN + i] * bf2f(u);
        }
        Zs[p] = s;
    }
    __syncthreads();

    // ---- phase 4: y0 = BN3'(z @ w3^T)  [256 outs], fp32 from global weights ----
    {
        int j = tid & 255, qh = tid >> 8;
        const float* wrow = w3 + j*128;
        float s3 = g3[j] * rsqrtf(v3[j] + BN_EPS);
        float cb = b3[j] - m3[j], bej = be3[j];
#pragma unroll
        for (int qq = 0; qq < 4; ++qq) {
            int q = qh*4 + qq;
            float accv = 0.0f;
            const float* zq = Zs + q*128;
            for (int k = 0; k < 128; k += 4) {
                float4 wv = *(const float4*)(wrow + k);
                accv += zq[k]*wv.x + zq[k+1]*wv.y + zq[k+2]*wv.z + zq[k+3]*wv.w;
            }
            float S = Sq[q];
            Y0s[q*256 + j] = s3*(accv + S*cb) + S*bej;
        }
    }
    __syncthreads();

    // ---- phase 5: g1 (256->128) ----
    {
        int j = tid & 127, qq = tid >> 7;
        const float* wrow = gw1 + j*256;
        float s = gg1[j] * rsqrtf(gv1[j] + BN_EPS);
        float cb = gb1[j] - gm1[j], bej = gbe1[j];
#pragma unroll
        for (int t = 0; t < 2; ++t) {
            int q = qq*2 + t;
            float accv = 0.0f;
            const float* yq = Y0s + q*256;
            for (int k = 0; k < 256; k += 4) {
                float4 wv = *(const float4*)(wrow + k);
                accv += yq[k]*wv.x + yq[k+1]*wv.y + yq[k+2]*wv.z + yq[k+3]*wv.w;
            }
            Y1s[q*128 + j] = fmaxf(s*(accv + cb) + bej, 0.0f);
        }
    }
    __syncthreads();

    // ---- phase 6: g2 (128->64) ----
    {
        int j = tid & 63, q = tid >> 6;
        const float* wrow = gw2 + j*128;
        float s = gg2[j] * rsqrtf(gv2[j] + BN_EPS);
        float cb = gb2[j] - gm2[j], bej = gbe2[j];
        float accv = 0.0f;
        const float* yq = Y1s + q*128;
        for (int k = 0; k < 128; k += 4) {
            float4 wv = *(const float4*)(wrow + k);
            accv += yq[k]*wv.x + yq[k+1]*wv.y + yq[k+2]*wv.z + yq[k+3]*wv.w;
        }
        Y2s[q*64 + j] = fmaxf(s*(accv + cb) + bej, 0.0f);
    }
    __syncthreads();

    // ---- phase 7: g3 (64->3) ----
    if (tid < 32) {
        int q = tid >> 2, jj = tid & 3;
        if (jj < 3) {
            const float* wrow = gw3 + jj*64;
            float accv = 0.0f;
            const float* yq = Y2s + q*64;
            for (int k = 0; k < 64; ++k) accv += yq[k]*wrow[k];
            out[(qbase + q)*3 + jj] = accv + gb3[jj];
        }
    }
}

extern "C" void kernel_launch(void* const* d_in, const int* in_sizes, int n_in,
                              void* d_out, int out_size, void* d_ws, size_t ws_size,
                              hipStream_t stream)
{
    const float* pq    = (const float*)d_in[0];
    const float* pc    = (const float*)d_in[1];
    const float* hc    = (const float*)d_in[2];
    const float* w_xyz = (const float*)d_in[3];
    const float* b_xyz = (const float*)d_in[4];
    const float* w1    = (const float*)d_in[5];
    const float* b1    = (const float*)d_in[6];
    const float* g1    = (const float*)d_in[7];
    const float* be1   = (const float*)d_in[8];
    const float* m1    = (const float*)d_in[9];
    const float* v1    = (const float*)d_in[10];
    const float* w2    = (const float*)d_in[11];
    const float* b2    = (const float*)d_in[12];
    const float* g2    = (const float*)d_in[13];
    const float* be2   = (const float*)d_in[14];
    const float* m2    = (const float*)d_in[15];
    const float* v2    = (const float*)d_in[16];
    const float* w3    = (const float*)d_in[17];
    const float* b3    = (const float*)d_in[18];
    const float* g3    = (const float*)d_in[19];
    const float* be3   = (const float*)d_in[20];
    const float* m3    = (const float*)d_in[21];
    const float* v3    = (const float*)d_in[22];
    const float* gw1   = (const float*)d_in[23];
    const float* gb1   = (const float*)d_in[24];
    const float* gg1   = (const float*)d_in[25];
    const float* gbe1  = (const float*)d_in[26];
    const float* gm1   = (const float*)d_in[27];
    const float* gv1   = (const float*)d_in[28];
    const float* gw2   = (const float*)d_in[29];
    const float* gb2   = (const float*)d_in[30];
    const float* gg2   = (const float*)d_in[31];
    const float* gbe2  = (const float*)d_in[32];
    const float* gm2   = (const float*)d_in[33];
    const float* gv2   = (const float*)d_in[34];
    const float* gw3   = (const float*)d_in[35];
    const float* gb3   = (const float*)d_in[36];

    int*   idx_buf = (int*)d_ws;
    float* cw_buf  = (float*)((char*)d_ws + (size_t)BB*NQ*KNN*sizeof(int));

    dim3 kgrid(NQ, BB);
    knn_kernel<<<kgrid, 256, 0, stream>>>(pq, pc, idx_buf, cw_buf);

    int mblocks = (BB*NQ) / QB;
    mlp_kernel<<<mblocks, 512, 0, stream>>>(pq, pc, hc, w_xyz, b_xyz,
        w1, b1, g1, be1, m1, v1,
        w2, b2, g2, be2, m2, v2,
        w3, b3, g3, be3, m3, v3,
        gw1, gb1, gg1, gbe1, gm1, gv1,
        gw2, gb2, gg2, gbe2, gm2, gv2,
        gw3, gb3,
        idx_buf, cw_buf, (float*)d_out);
}